// Round 6
// baseline (627.504 us; speedup 1.0000x reference)
//
#include <hip/hip_runtime.h>
#include <hip/hip_bf16.h>

#define Bc 4
#define Tc 16
#define Nc 1024
#define Ec 16384
#define FIN 128
#define Hc 256
#define FFc 1024
#define NHc 8
#define Lc 2
#define HDc 32
#define Gc 64
#define EPSc 1e-5f

// ---------------- per graph: invdeg, cw, CSR(off,elist), zero uv ----------------
__global__ void csr_kernel(const int* __restrict__ ei, float* __restrict__ invdeg,
                           float* __restrict__ cw, int* __restrict__ off,
                           int* __restrict__ elist, float* __restrict__ uv) {
    __shared__ int degs[Nc];
    __shared__ float inv[Nc];
    __shared__ float cl[Nc];
    __shared__ int part[256];
    __shared__ int offs[Nc + 1];
    int g = blockIdx.x, t = threadIdx.x;   // 256 threads
    const int* src = ei + (size_t)g * 2 * Ec;
    const int* dst = src + Ec;
    uv[g * 512 + t] = 0.f;
    uv[g * 512 + 256 + t] = 0.f;
    for (int i = t; i < Nc; i += 256) { degs[i] = 0; cl[i] = 0.f; }
    __syncthreads();
    for (int e = t; e < Ec; e += 256) atomicAdd(&degs[dst[e] & (Nc - 1)], 1);
    __syncthreads();
    for (int i = t; i < Nc; i += 256) {
        float iv = 1.0f / fmaxf((float)degs[i], 1.0f);
        inv[i] = iv;
        invdeg[g * Nc + i] = iv;
    }
    __syncthreads();
    for (int e = t; e < Ec; e += 256) atomicAdd(&cl[src[e] & (Nc - 1)], inv[dst[e] & (Nc - 1)]);
    __syncthreads();
    for (int i = t; i < Nc; i += 256) cw[g * Nc + i] = cl[i];
    // exclusive prefix sum of degs -> offs[0..1024]
    int b = t * 4;
    int d0 = degs[b], d1 = degs[b + 1], d2 = degs[b + 2], d3 = degs[b + 3];
    int s0 = d0 + d1 + d2 + d3;
    part[t] = s0;
    __syncthreads();
    for (int ofs = 1; ofs < 256; ofs <<= 1) {
        int v = (t >= ofs) ? part[t - ofs] : 0;
        __syncthreads();
        part[t] += v;
        __syncthreads();
    }
    int run = part[t] - s0;              // exclusive
    offs[b] = run;
    offs[b + 1] = run + d0;
    offs[b + 2] = run + d0 + d1;
    offs[b + 3] = run + d0 + d1 + d2;
    if (t == 255) offs[Nc] = part[255];
    __syncthreads();
    for (int i = t; i < Nc + 1; i += 256) off[g * 1032 + i] = offs[i];
    for (int i = t; i < Nc; i += 256) degs[i] = offs[i];   // cursors
    __syncthreads();
    for (int e = t; e < Ec; e += 256) {
        int d = dst[e] & (Nc - 1);
        int slot = atomicAdd(&degs[d], 1);
        elist[(size_t)g * Ec + slot] = src[e] & (Nc - 1);
    }
}

// ---------------- SAGE layer1 + reduce: 32-row tiles, fp32 VALU ----------------
__global__ __launch_bounds__(256) void sage_kernel(
        const float* __restrict__ x, const int* __restrict__ elist,
        const int* __restrict__ off, const float* __restrict__ invdeg,
        const float* __restrict__ cw, const float* __restrict__ Wl,
        const float* __restrict__ Wr, const float* __restrict__ bias,
        float* __restrict__ uv) {
    __shared__ float aggL[32 * 129];     // 16512 B (pad 129 kills stride-128 conflicts)
    __shared__ float xL[32 * 129];       // 16512 B
    int tid = threadIdx.x;
    int bid = blockIdx.x;                // g*32 + cc
    int g = bid >> 5, cc = bid & 31, r0 = cc * 32;
    const int* el = elist + (size_t)g * Ec;
    const float* xg = x + (size_t)g * Nc * FIN;

    // phase A: CSR mean-aggregate into LDS, item = (local row, 8-dim chunk)
    for (int it = tid; it < 512; it += 256) {
        int lr = it >> 4, ch = it & 15;
        int n = r0 + lr;
        int o0 = off[g * 1032 + n], o1 = off[g * 1032 + n + 1];
        float4 a0 = make_float4(0.f, 0.f, 0.f, 0.f);
        float4 a1 = make_float4(0.f, 0.f, 0.f, 0.f);
        const float* xc = xg + ch * 8;
        for (int e = o0; e < o1; ++e) {
            int s = el[e] & (Nc - 1);
            const float4* xp = (const float4*)(xc + (size_t)s * FIN);
            float4 v0 = xp[0], v1 = xp[1];
            a0.x += v0.x; a0.y += v0.y; a0.z += v0.z; a0.w += v0.w;
            a1.x += v1.x; a1.y += v1.y; a1.z += v1.z; a1.w += v1.w;
        }
        float iv = invdeg[g * Nc + n];
        float* dst = &aggL[lr * 129 + ch * 8];
        dst[0] = a0.x * iv; dst[1] = a0.y * iv; dst[2] = a0.z * iv; dst[3] = a0.w * iv;
        dst[4] = a1.x * iv; dst[5] = a1.y * iv; dst[6] = a1.z * iv; dst[7] = a1.w * iv;
    }
    // stage x tile
    for (int i = tid; i < 32 * 128; i += 256) {
        int lr = i >> 7, k = i & 127;
        xL[lr * 129 + k] = xg[(size_t)(r0 + lr) * FIN + k];
    }
    __syncthreads();

    // phase B: thread c computes column c for all 32 rows; k tiled by 8 for b128 LDS reads
    int c = tid;
    float b0 = bias[c];
    float acc[32];
#pragma unroll
    for (int r = 0; r < 32; ++r) acc[r] = b0;
    for (int k0 = 0; k0 < 128; k0 += 8) {
        float wl[8], wr[8];
#pragma unroll
        for (int j = 0; j < 8; ++j) {
            wl[j] = Wl[(size_t)(k0 + j) * Hc + c];
            wr[j] = Wr[(size_t)(k0 + j) * Hc + c];
        }
#pragma unroll
        for (int r = 0; r < 32; ++r) {
            const float4 a0 = *(const float4*)&aggL[r * 129 + k0];
            const float4 a1 = *(const float4*)&aggL[r * 129 + k0 + 4];
            const float4 x0 = *(const float4*)&xL[r * 129 + k0];
            const float4 x1 = *(const float4*)&xL[r * 129 + k0 + 4];
            float s = a0.x * wl[0] + a0.y * wl[1] + a0.z * wl[2] + a0.w * wl[3]
                    + a1.x * wl[4] + a1.y * wl[5] + a1.z * wl[6] + a1.w * wl[7]
                    + x0.x * wr[0] + x0.y * wr[1] + x0.z * wr[2] + x0.w * wr[3]
                    + x1.x * wr[4] + x1.y * wr[5] + x1.z * wr[6] + x1.w * wr[7];
            acc[r] += s;
        }
    }
    // epilogue: relu, u (cw-weighted) and v column sums
    float su = 0.f, sv = 0.f;
#pragma unroll
    for (int r = 0; r < 32; ++r) {
        float val = fmaxf(acc[r], 0.f);
        sv += val;
        su += cw[g * Nc + r0 + r] * val;
    }
    atomicAdd(&uv[g * 512 + c], su);
    atomicAdd(&uv[g * 512 + 256 + c], sv);
}

// ---------------- emb = u/N @ Wl2 + bl2 + v/N @ Wr2 ----------------
__global__ void emb_kernel(const float* __restrict__ uv, const float* __restrict__ Wl2,
                           const float* __restrict__ bl2, const float* __restrict__ Wr2,
                           float* __restrict__ h) {
    __shared__ float s[512];
    int g = blockIdx.x, o = threadIdx.x;
    s[o] = uv[g * 512 + o] * (1.0f / Nc);
    s[o + 256] = uv[g * 512 + o + 256] * (1.0f / Nc);
    __syncthreads();
    float val = bl2[o];
    for (int k = 0; k < 256; ++k) {
        val += s[k] * Wl2[(size_t)k * Hc + o];
        val += s[k + 256] * Wr2[(size_t)k * Hc + o];
    }
    h[g * Hc + o] = val;
}

// ---------------- transformer ----------------
__global__ void qkv_kernel(const float* __restrict__ h, const float* __restrict__ Wqkv,
                           const float* __restrict__ bqkv, float* __restrict__ qkv, int l) {
    __shared__ float hr[256];
    int bid = blockIdx.x;            // 64 rows * 3 segs
    int gi = bid / 3, seg = bid % 3;
    hr[threadIdx.x] = h[gi * Hc + threadIdx.x];
    __syncthreads();
    int col = seg * 256 + threadIdx.x;
    const float* W = Wqkv + (size_t)l * Hc * 768;
    float val = bqkv[(size_t)l * 768 + col];
    for (int k = 0; k < 256; ++k) val += hr[k] * W[(size_t)k * 768 + col];
    qkv[gi * 768 + col] = val;
}

__global__ void attn_kernel(const float* __restrict__ qkv, float* __restrict__ ctx) {
    __shared__ float qs[16][32], ks[16][32], vs[16][32], sc[16][16];
    int bid = blockIdx.x;            // b*8 + head
    int b = bid >> 3, hd = bid & 7;
    int tid = threadIdx.x;
    for (int idx = tid; idx < 512; idx += 256) {
        int t = idx >> 5, d = idx & 31;
        const float* base = qkv + (size_t)(b * 16 + t) * 768 + hd * 32 + d;
        qs[t][d] = base[0]; ks[t][d] = base[256]; vs[t][d] = base[512];
    }
    __syncthreads();
    {
        int i = tid >> 4, j = tid & 15;
        float s = 0.f;
#pragma unroll
        for (int d = 0; d < 32; ++d) s += qs[i][d] * ks[j][d];
        sc[i][j] = s * 0.17677669529663687f;   // 1/sqrt(32)
    }
    __syncthreads();
    if (tid < 16) {
        int i = tid;
        float m = sc[i][0];
        for (int j = 1; j < 16; ++j) m = fmaxf(m, sc[i][j]);
        float e[16], sum = 0.f;
        for (int j = 0; j < 16; ++j) { e[j] = expf(sc[i][j] - m); sum += e[j]; }
        float invs = 1.0f / sum;
        for (int j = 0; j < 16; ++j) sc[i][j] = e[j] * invs;
    }
    __syncthreads();
    for (int idx = tid; idx < 512; idx += 256) {
        int i = idx >> 5, d = idx & 31;
        float o = 0.f;
#pragma unroll
        for (int j = 0; j < 16; ++j) o += sc[i][j] * vs[j][d];
        ctx[(size_t)(b * 16 + i) * 256 + hd * 32 + d] = o;
    }
}

__global__ void proj_ln_kernel(float* __restrict__ h, const float* __restrict__ ctx,
                               const float* __restrict__ Wo, const float* __restrict__ bo,
                               const float* __restrict__ s1, const float* __restrict__ b1,
                               int l) {
    __shared__ float cx[256];
    __shared__ float red[256];
    int gi = blockIdx.x, col = threadIdx.x;
    cx[col] = ctx[gi * 256 + col];
    __syncthreads();
    const float* W = Wo + (size_t)l * 65536;
    float val = h[gi * 256 + col] + bo[(size_t)l * 256 + col];
    for (int k = 0; k < 256; ++k) val += cx[k] * W[(size_t)k * 256 + col];
    red[col] = val; __syncthreads();
    for (int s = 128; s > 0; s >>= 1) { if (col < s) red[col] += red[col + s]; __syncthreads(); }
    float m = red[0] * (1.0f / 256.0f);
    __syncthreads();
    float d = val - m;
    red[col] = d * d; __syncthreads();
    for (int s = 128; s > 0; s >>= 1) { if (col < s) red[col] += red[col + s]; __syncthreads(); }
    float var = red[0] * (1.0f / 256.0f);
    h[gi * 256 + col] = d * rsqrtf(var + EPSc) * s1[(size_t)l * 256 + col]
                        + b1[(size_t)l * 256 + col];
}

__global__ void ffn1_kernel(const float* __restrict__ h, const float* __restrict__ W1,
                            const float* __restrict__ b1, float* __restrict__ f, int l) {
    __shared__ float hr[256];
    int gi = blockIdx.x;
    hr[threadIdx.x] = h[gi * 256 + threadIdx.x];
    __syncthreads();
    const float* W = W1 + (size_t)l * 262144;
    for (int c = 0; c < 4; ++c) {
        int col = threadIdx.x + c * 256;
        float val = b1[(size_t)l * 1024 + col];
        for (int k = 0; k < 256; ++k) val += hr[k] * W[(size_t)k * 1024 + col];
        f[gi * 1024 + col] = fmaxf(val, 0.f);
    }
}

__global__ void ffn2_ln_kernel(float* __restrict__ h, const float* __restrict__ f,
                               const float* __restrict__ W2, const float* __restrict__ b2,
                               const float* __restrict__ s2, const float* __restrict__ b2l,
                               int l) {
    __shared__ float fr[1024];
    __shared__ float red[256];
    int gi = blockIdx.x, col = threadIdx.x;
    for (int i = col; i < 1024; i += 256) fr[i] = f[gi * 1024 + i];
    __syncthreads();
    const float* W = W2 + (size_t)l * 262144;
    float val = h[gi * 256 + col] + b2[(size_t)l * 256 + col];
    for (int k = 0; k < 1024; ++k) val += fr[k] * W[(size_t)k * 256 + col];
    red[col] = val; __syncthreads();
    for (int s = 128; s > 0; s >>= 1) { if (col < s) red[col] += red[col + s]; __syncthreads(); }
    float m = red[0] * (1.0f / 256.0f);
    __syncthreads();
    float d = val - m;
    red[col] = d * d; __syncthreads();
    for (int s = 128; s > 0; s >>= 1) { if (col < s) red[col] += red[col + s]; __syncthreads(); }
    float var = red[0] * (1.0f / 256.0f);
    h[gi * 256 + col] = d * rsqrtf(var + EPSc) * s2[(size_t)l * 256 + col]
                        + b2l[(size_t)l * 256 + col];
}

__global__ void fc_kernel(const float* __restrict__ h, const float* __restrict__ fcW,
                          const float* __restrict__ fcb, float* __restrict__ out) {
    int tid = threadIdx.x;
    if (tid < Bc * 10) {
        int b = tid / 10, c = tid % 10;
        const float* hr = h + (size_t)(b * 16 + 15) * 256;
        float val = fcb[c];
        for (int k = 0; k < 256; ++k) val += hr[k] * fcW[(size_t)k * 10 + c];
        out[tid] = val;                 // fp32 output — reference output dtype is float32
    }
}

extern "C" void kernel_launch(void* const* d_in, const int* in_sizes, int n_in,
                              void* d_out, int out_size, void* d_ws, size_t ws_size,
                              hipStream_t stream) {
    (void)in_sizes; (void)n_in; (void)out_size; (void)ws_size;
    const float* x    = (const float*)d_in[0];
    const int*   ei   = (const int*)d_in[1];
    const float* s1Wl = (const float*)d_in[2];
    const float* s1bl = (const float*)d_in[3];
    const float* s1Wr = (const float*)d_in[4];
    const float* s2Wl = (const float*)d_in[5];
    const float* s2bl = (const float*)d_in[6];
    const float* s2Wr = (const float*)d_in[7];
    const float* Wqkv = (const float*)d_in[8];
    const float* bqkv = (const float*)d_in[9];
    const float* Wo   = (const float*)d_in[10];
    const float* bo   = (const float*)d_in[11];
    const float* ln1s = (const float*)d_in[12];
    const float* ln1b = (const float*)d_in[13];
    const float* W1   = (const float*)d_in[14];
    const float* b1   = (const float*)d_in[15];
    const float* W2   = (const float*)d_in[16];
    const float* b2   = (const float*)d_in[17];
    const float* ln2s = (const float*)d_in[18];
    const float* ln2b = (const float*)d_in[19];
    const float* fcW  = (const float*)d_in[20];
    const float* fcb  = (const float*)d_in[21];

    // workspace layout (total ~5.7 MB)
    char* ws = (char*)d_ws;
    float* invdeg = (float*)(ws + 256);           // 64*1024*4 = 262144
    float* cw     = (float*)(ws + 262400);        // 262144
    int*   off    = (int*)(ws + 524544);          // 64*1032*4 = 264192
    int*   elist  = (int*)(ws + 788736);          // 64*16384*4 = 4194304
    float* uv     = (float*)(ws + 4983040);       // 64*512*4 = 131072
    float* h      = (float*)(ws + 5114112);       // 64*256*4 = 65536
    float* qkv    = (float*)(ws + 5179648);       // 64*768*4 = 196608
    float* ctx    = (float*)(ws + 5376256);       // 65536
    float* ffn    = (float*)(ws + 5441792);       // 64*1024*4 = 262144
                                                  // end = 5703936

    csr_kernel<<<Gc, 256, 0, stream>>>(ei, invdeg, cw, off, elist, uv);
    sage_kernel<<<Gc * 32, 256, 0, stream>>>(x, elist, off, invdeg, cw, s1Wl, s1Wr, s1bl, uv);
    emb_kernel<<<Gc, 256, 0, stream>>>(uv, s2Wl, s2bl, s2Wr, h);
    for (int l = 0; l < Lc; ++l) {
        qkv_kernel<<<Gc * 3, 256, 0, stream>>>(h, Wqkv, bqkv, qkv, l);
        attn_kernel<<<Bc * NHc, 256, 0, stream>>>(qkv, ctx);
        proj_ln_kernel<<<Gc, 256, 0, stream>>>(h, ctx, Wo, bo, ln1s, ln1b, l);
        ffn1_kernel<<<Gc, 256, 0, stream>>>(h, W1, b1, ffn, l);
        ffn2_ln_kernel<<<Gc, 256, 0, stream>>>(h, ffn, W2, b2, ln2s, ln2b, l);
    }
    fc_kernel<<<1, 64, 0, stream>>>(h, fcW, fcb, (float*)d_out);
}

// Round 7
// 480.014 us; speedup vs baseline: 1.3073x; 1.3073x over previous
//
#include <hip/hip_runtime.h>
#include <hip/hip_bf16.h>

#define Bc 4
#define Tc 16
#define Nc 1024
#define Ec 16384
#define FIN 128
#define Hc 256
#define FFc 1024
#define NHc 8
#define Lc 2
#define HDc 32
#define Gc 64
#define EPSc 1e-5f

typedef __bf16 v8bf __attribute__((ext_vector_type(8)));
typedef float v4f __attribute__((ext_vector_type(4)));

// ---------------- W pack: Wcat[256][256]=[Wl1;Wr1] -> MFMA B-frag order, bf16 hi+lo ----------------
// packed[((kc*16+nt)*64+lane)*8+j] = Wcat[kc*32+(lane>>4)*8+j][nt*16+(lane&15)]
__global__ void pack_w_kernel(const float* __restrict__ Wl, const float* __restrict__ Wr,
                              __bf16* __restrict__ pH, __bf16* __restrict__ pL) {
    int bid = blockIdx.x;            // 0..127 = kc*16+nt
    int t = threadIdx.x;             // 512
    int lane = t >> 3, j = t & 7;
    int kc = bid >> 4, nt = bid & 15;
    int k = kc * 32 + ((lane >> 4) << 3) + j;
    int n = nt * 16 + (lane & 15);
    float w = (k < 128) ? Wl[(size_t)k * Hc + n] : Wr[(size_t)(k - 128) * Hc + n];
    __bf16 hi = (__bf16)w;
    __bf16 lo = (__bf16)(w - (float)hi);
    pH[bid * 512 + t] = hi;
    pL[bid * 512 + t] = lo;
}

// ---------------- per graph: invdeg, cw, CSR(off,elist), zero uv ----------------
__global__ void csr_kernel(const int* __restrict__ ei, float* __restrict__ invdeg,
                           float* __restrict__ cw, int* __restrict__ off,
                           int* __restrict__ elist, float* __restrict__ uv) {
    __shared__ int degs[Nc];
    __shared__ float inv[Nc];
    __shared__ float cl[Nc];
    __shared__ int part[256];
    __shared__ int offs[Nc + 1];
    int g = blockIdx.x, t = threadIdx.x;   // 256 threads
    const int* src = ei + (size_t)g * 2 * Ec;
    const int* dst = src + Ec;
    uv[g * 512 + t] = 0.f;
    uv[g * 512 + 256 + t] = 0.f;
    for (int i = t; i < Nc; i += 256) { degs[i] = 0; cl[i] = 0.f; }
    __syncthreads();
    for (int e = t; e < Ec; e += 256) atomicAdd(&degs[dst[e] & (Nc - 1)], 1);
    __syncthreads();
    for (int i = t; i < Nc; i += 256) {
        float iv = 1.0f / fmaxf((float)degs[i], 1.0f);
        inv[i] = iv;
        invdeg[g * Nc + i] = iv;
    }
    __syncthreads();
    for (int e = t; e < Ec; e += 256) atomicAdd(&cl[src[e] & (Nc - 1)], inv[dst[e] & (Nc - 1)]);
    __syncthreads();
    for (int i = t; i < Nc; i += 256) cw[g * Nc + i] = cl[i];
    int b = t * 4;
    int d0 = degs[b], d1 = degs[b + 1], d2 = degs[b + 2], d3 = degs[b + 3];
    int s0 = d0 + d1 + d2 + d3;
    part[t] = s0;
    __syncthreads();
    for (int ofs = 1; ofs < 256; ofs <<= 1) {
        int v = (t >= ofs) ? part[t - ofs] : 0;
        __syncthreads();
        part[t] += v;
        __syncthreads();
    }
    int run = part[t] - s0;              // exclusive
    offs[b] = run;
    offs[b + 1] = run + d0;
    offs[b + 2] = run + d0 + d1;
    offs[b + 3] = run + d0 + d1 + d2;
    if (t == 255) offs[Nc] = part[255];
    __syncthreads();
    for (int i = t; i < Nc + 1; i += 256) off[g * 1032 + i] = offs[i];
    for (int i = t; i < Nc; i += 256) degs[i] = offs[i];   // cursors
    __syncthreads();
    for (int e = t; e < Ec; e += 256) {
        int d = dst[e] & (Nc - 1);
        int slot = atomicAdd(&degs[d], 1);
        elist[(size_t)g * Ec + slot] = src[e] & (Nc - 1);
    }
}

// ---------------- SAGE layer1 + reduce: gather -> MFMA (hi/lo bf16 split) -> u,v ----------------
__global__ __launch_bounds__(256) void sage_kernel(
        const float* __restrict__ x, const int* __restrict__ elist,
        const int* __restrict__ off, const float* __restrict__ invdeg,
        const float* __restrict__ cw, const __bf16* __restrict__ pH,
        const __bf16* __restrict__ pL, const float* __restrict__ bias,
        float* __restrict__ uv) {
    __shared__ float aggL[32 * 132];     // 16896 B (stride 132: 4-bank row offset, 2-way free)
    __shared__ float xL[32 * 132];       // 16896 B
    __shared__ float lu[256], lv[256];
    int tid = threadIdx.x;
    int bid = blockIdx.x;                // g*32 + cc
    int g = bid >> 5, cc = bid & 31, r0 = cc * 32;
    const int* el = elist + (size_t)g * Ec;
    const float* xg = x + (size_t)g * Nc * FIN;
    lu[tid] = 0.f; lv[tid] = 0.f;

    // phase A: CSR mean-aggregate into LDS, item = (local row, 8-dim chunk)
    for (int it = tid; it < 512; it += 256) {
        int lr = it >> 4, ch = it & 15;
        int n = r0 + lr;
        int o0 = off[g * 1032 + n], o1 = off[g * 1032 + n + 1];
        float4 a0 = make_float4(0.f, 0.f, 0.f, 0.f);
        float4 a1 = make_float4(0.f, 0.f, 0.f, 0.f);
        const float* xc = xg + ch * 8;
        for (int e = o0; e < o1; ++e) {
            int s = el[e] & (Nc - 1);
            const float4* xp = (const float4*)(xc + (size_t)s * FIN);
            float4 v0 = xp[0], v1 = xp[1];
            a0.x += v0.x; a0.y += v0.y; a0.z += v0.z; a0.w += v0.w;
            a1.x += v1.x; a1.y += v1.y; a1.z += v1.z; a1.w += v1.w;
        }
        float iv = invdeg[g * Nc + n];
        float* dp = &aggL[lr * 132 + ch * 8];
        dp[0] = a0.x * iv; dp[1] = a0.y * iv; dp[2] = a0.z * iv; dp[3] = a0.w * iv;
        dp[4] = a1.x * iv; dp[5] = a1.y * iv; dp[6] = a1.z * iv; dp[7] = a1.w * iv;
    }
    // stage own-row x tile
    for (int i = tid; i < 32 * 128; i += 256) {
        int lr = i >> 7, k = i & 127;
        xL[lr * 132 + k] = xg[(size_t)(r0 + lr) * FIN + k];
    }
    __syncthreads();

    // phase B: MFMA. 4 waves: mt = w&1 (16-row tile), nh = w>>1 (8 n-tiles)
    int w = tid >> 6, lane = tid & 63, quad = lane >> 4;
    int mt = w & 1, nh = w >> 1;
    int lrow = mt * 16 + (lane & 15);
    v4f acc[8];
#pragma unroll
    for (int i = 0; i < 8; ++i) acc[i] = (v4f)0.f;
    for (int kc = 0; kc < 8; ++kc) {
        const float* ap = (kc < 4) ? &aggL[lrow * 132 + kc * 32 + quad * 8]
                                   : &xL[lrow * 132 + (kc - 4) * 32 + quad * 8];
        float4 f0 = *(const float4*)ap;
        float4 f1 = *(const float4*)(ap + 4);
        float av[8] = {f0.x, f0.y, f0.z, f0.w, f1.x, f1.y, f1.z, f1.w};
        v8bf aH, aL;
#pragma unroll
        for (int j = 0; j < 8; ++j) {
            __bf16 hbit = (__bf16)av[j];
            aH[j] = hbit;
            aL[j] = (__bf16)(av[j] - (float)hbit);
        }
#pragma unroll
        for (int i = 0; i < 8; ++i) {
            int nt = nh * 8 + i;
            v8bf bH = *(const v8bf*)(pH + ((size_t)(kc * 16 + nt) * 64 + lane) * 8);
            v8bf bL = *(const v8bf*)(pL + ((size_t)(kc * 16 + nt) * 64 + lane) * 8);
            acc[i] = __builtin_amdgcn_mfma_f32_16x16x32_bf16(aH, bH, acc[i], 0, 0, 0);
            acc[i] = __builtin_amdgcn_mfma_f32_16x16x32_bf16(aL, bH, acc[i], 0, 0, 0);
            acc[i] = __builtin_amdgcn_mfma_f32_16x16x32_bf16(aH, bL, acc[i], 0, 0, 0);
        }
    }

    // epilogue: bias+relu; u (cw-weighted) / v column sums. C/D: col=lane&15, row=quad*4+r
    float c4[4];
    int nb = g * Nc + r0 + mt * 16 + quad * 4;
#pragma unroll
    for (int r = 0; r < 4; ++r) c4[r] = cw[nb + r];
#pragma unroll
    for (int i = 0; i < 8; ++i) {
        int col = (nh * 8 + i) * 16 + (lane & 15);
        float bcol = bias[col];
        float su = 0.f, sv = 0.f;
#pragma unroll
        for (int r = 0; r < 4; ++r) {
            float val = fmaxf(acc[i][r] + bcol, 0.f);
            sv += val;
            su += c4[r] * val;
        }
        su += __shfl_xor(su, 16); sv += __shfl_xor(sv, 16);
        su += __shfl_xor(su, 32); sv += __shfl_xor(sv, 32);
        if (quad == 0) { atomicAdd(&lu[col], su); atomicAdd(&lv[col], sv); }
    }
    __syncthreads();
    atomicAdd(&uv[g * 512 + tid], lu[tid]);
    atomicAdd(&uv[g * 512 + 256 + tid], lv[tid]);
}

// ---------------- emb = u/N @ Wl2 + bl2 + v/N @ Wr2 ----------------
__global__ void emb_kernel(const float* __restrict__ uv, const float* __restrict__ Wl2,
                           const float* __restrict__ bl2, const float* __restrict__ Wr2,
                           float* __restrict__ h) {
    __shared__ float s[512];
    int g = blockIdx.x, o = threadIdx.x;
    s[o] = uv[g * 512 + o] * (1.0f / Nc);
    s[o + 256] = uv[g * 512 + o + 256] * (1.0f / Nc);
    __syncthreads();
    float val = bl2[o];
    for (int k = 0; k < 256; ++k) {
        val += s[k] * Wl2[(size_t)k * Hc + o];
        val += s[k + 256] * Wr2[(size_t)k * Hc + o];
    }
    h[g * Hc + o] = val;
}

// ---------------- qkv: token x seg parallel ----------------
__global__ void qkv_kernel(const float* __restrict__ h, const float* __restrict__ Wqkv,
                           const float* __restrict__ bqkv, float* __restrict__ qkv, int l) {
    __shared__ float hr[256];
    int bid = blockIdx.x;            // 64 rows * 3 segs
    int gi = bid / 3, seg = bid % 3;
    hr[threadIdx.x] = h[gi * Hc + threadIdx.x];
    __syncthreads();
    int col = seg * 256 + threadIdx.x;
    const float* W = Wqkv + (size_t)l * Hc * 768;
    float val = bqkv[(size_t)l * 768 + col];
    for (int k = 0; k < 256; ++k) val += hr[k] * W[(size_t)k * 768 + col];
    qkv[gi * 768 + col] = val;
}

// ---------------- fused per-token layer: attn + proj + ln1 + ffn + ln2 (+ fc on last) ----------------
#define KVS 516   // kv row stride (516%32==4 -> 2-way bank alias, free)
__global__ __launch_bounds__(256) void layer_kernel(
        float* __restrict__ h, const float* __restrict__ qkvg,
        const float* __restrict__ Wo, const float* __restrict__ bo,
        const float* __restrict__ s1, const float* __restrict__ b1ln,
        const float* __restrict__ W1, const float* __restrict__ bf1,
        const float* __restrict__ W2, const float* __restrict__ bf2,
        const float* __restrict__ s2, const float* __restrict__ b2ln,
        const float* __restrict__ fcW, const float* __restrict__ fcb,
        float* __restrict__ out, int l, int last) {
    __shared__ float kv[16 * KVS];   // K|V of own batch: [j][0:256]=K, [256:512]=V
    __shared__ float q[256];
    __shared__ float sc[8][17];
    __shared__ float ctx[256];
    __shared__ float h1[256];
    __shared__ float fL[1024];
    __shared__ float red[256];
    int t = blockIdx.x, tid = threadIdx.x;
    int b = t >> 4;
    const float* qb = qkvg + (size_t)(b * 16) * 768;
    for (int i = tid; i < 8192; i += 256) {
        int j = i >> 9, d = i & 511;
        kv[j * KVS + d] = qb[(size_t)j * 768 + 256 + d];
    }
    q[tid] = qkvg[(size_t)t * 768 + tid];
    __syncthreads();
    if (tid < 128) {
        int hd = tid >> 4, j = tid & 15;
        float s = 0.f;
#pragma unroll
        for (int d = 0; d < 32; ++d) s += q[hd * 32 + d] * kv[j * KVS + hd * 32 + d];
        sc[hd][j] = s * 0.17677669529663687f;   // 1/sqrt(32)
    }
    __syncthreads();
    if (tid < 8) {
        float m = sc[tid][0];
        for (int j = 1; j < 16; ++j) m = fmaxf(m, sc[tid][j]);
        float e[16], sum = 0.f;
        for (int j = 0; j < 16; ++j) { e[j] = expf(sc[tid][j] - m); sum += e[j]; }
        float inv = 1.0f / sum;
        for (int j = 0; j < 16; ++j) sc[tid][j] = e[j] * inv;
    }
    __syncthreads();
    {
        int hd = tid >> 5, d = tid & 31;
        float o = 0.f;
#pragma unroll
        for (int j = 0; j < 16; ++j) o += sc[hd][j] * kv[j * KVS + 256 + hd * 32 + d];
        ctx[tid] = o;
    }
    __syncthreads();
    // proj + ln1
    const float* W = Wo + (size_t)l * 65536;
    float val = h[(size_t)t * 256 + tid] + bo[(size_t)l * 256 + tid];
    for (int k = 0; k < 256; ++k) val += ctx[k] * W[(size_t)k * 256 + tid];
    red[tid] = val; __syncthreads();
    for (int s = 128; s > 0; s >>= 1) { if (tid < s) red[tid] += red[tid + s]; __syncthreads(); }
    float m1 = red[0] * (1.0f / 256.0f);
    __syncthreads();
    float d1 = val - m1;
    red[tid] = d1 * d1; __syncthreads();
    for (int s = 128; s > 0; s >>= 1) { if (tid < s) red[tid] += red[tid + s]; __syncthreads(); }
    float v1 = red[0] * (1.0f / 256.0f);
    float h1v = d1 * rsqrtf(v1 + EPSc) * s1[(size_t)l * 256 + tid] + b1ln[(size_t)l * 256 + tid];
    h1[tid] = h1v;
    __syncthreads();
    // ffn1
    const float* Wa = W1 + (size_t)l * 262144;
    for (int c = 0; c < 4; ++c) {
        int col = tid + c * 256;
        float v2 = bf1[(size_t)l * 1024 + col];
        for (int k = 0; k < 256; ++k) v2 += h1[k] * Wa[(size_t)k * 1024 + col];
        fL[col] = fmaxf(v2, 0.f);
    }
    __syncthreads();
    // ffn2 + ln2
    const float* Wb = W2 + (size_t)l * 262144;
    float v3 = h1v + bf2[(size_t)l * 256 + tid];
    for (int k = 0; k < 1024; ++k) v3 += fL[k] * Wb[(size_t)k * 256 + tid];
    red[tid] = v3; __syncthreads();
    for (int s = 128; s > 0; s >>= 1) { if (tid < s) red[tid] += red[tid + s]; __syncthreads(); }
    float m2 = red[0] * (1.0f / 256.0f);
    __syncthreads();
    float d2 = v3 - m2;
    red[tid] = d2 * d2; __syncthreads();
    for (int s = 128; s > 0; s >>= 1) { if (tid < s) red[tid] += red[tid + s]; __syncthreads(); }
    float var2 = red[0] * (1.0f / 256.0f);
    float hn = d2 * rsqrtf(var2 + EPSc) * s2[(size_t)l * 256 + tid] + b2ln[(size_t)l * 256 + tid];
    h[(size_t)t * 256 + tid] = hn;
    // fc fold-in: last layer, token index 15 of each batch
    if (last && (t & 15) == 15) {
        __syncthreads();
        red[tid] = hn;
        __syncthreads();
        if (tid < 10) {
            float fv = fcb[tid];
            for (int k = 0; k < 256; ++k) fv += red[k] * fcW[(size_t)k * 10 + tid];
            out[b * 10 + tid] = fv;
        }
    }
}

extern "C" void kernel_launch(void* const* d_in, const int* in_sizes, int n_in,
                              void* d_out, int out_size, void* d_ws, size_t ws_size,
                              hipStream_t stream) {
    (void)in_sizes; (void)n_in; (void)out_size; (void)ws_size;
    const float* x    = (const float*)d_in[0];
    const int*   ei   = (const int*)d_in[1];
    const float* s1Wl = (const float*)d_in[2];
    const float* s1bl = (const float*)d_in[3];
    const float* s1Wr = (const float*)d_in[4];
    const float* s2Wl = (const float*)d_in[5];
    const float* s2bl = (const float*)d_in[6];
    const float* s2Wr = (const float*)d_in[7];
    const float* Wqkv = (const float*)d_in[8];
    const float* bqkv = (const float*)d_in[9];
    const float* Wo   = (const float*)d_in[10];
    const float* bo   = (const float*)d_in[11];
    const float* ln1s = (const float*)d_in[12];
    const float* ln1b = (const float*)d_in[13];
    const float* W1   = (const float*)d_in[14];
    const float* b1   = (const float*)d_in[15];
    const float* W2   = (const float*)d_in[16];
    const float* b2   = (const float*)d_in[17];
    const float* ln2s = (const float*)d_in[18];
    const float* ln2b = (const float*)d_in[19];
    const float* fcW  = (const float*)d_in[20];
    const float* fcb  = (const float*)d_in[21];

    // workspace layout (total ~5.64 MB)
    char* ws = (char*)d_ws;
    __bf16* packWH = (__bf16*)(ws + 0);           // 131072
    __bf16* packWL = (__bf16*)(ws + 131072);      // 131072
    float*  invdeg = (float*)(ws + 262144);       // 262144
    float*  cw     = (float*)(ws + 524288);       // 262144
    int*    off    = (int*)(ws + 786432);         // 264192
    int*    elist  = (int*)(ws + 1050624);        // 4194304
    float*  uv     = (float*)(ws + 5244928);      // 131072
    float*  h      = (float*)(ws + 5376000);      // 65536
    float*  qkvg   = (float*)(ws + 5441536);      // 196608
                                                  // end = 5638144

    pack_w_kernel<<<128, 512, 0, stream>>>(s1Wl, s1Wr, packWH, packWL);
    csr_kernel<<<Gc, 256, 0, stream>>>(ei, invdeg, cw, off, elist, uv);
    sage_kernel<<<Gc * 32, 256, 0, stream>>>(x, elist, off, invdeg, cw, packWH, packWL, s1bl, uv);
    emb_kernel<<<Gc, 256, 0, stream>>>(uv, s2Wl, s2bl, s2Wr, h);
    for (int l = 0; l < Lc; ++l) {
        qkv_kernel<<<Gc * 3, 256, 0, stream>>>(h, Wqkv, bqkv, qkvg, l);
        layer_kernel<<<Gc, 256, 0, stream>>>(h, qkvg, Wo, bo, ln1s, ln1b, W1, b1,
                                             W2, b2, ln2s, ln2b, fcW, fcb,
                                             (float*)d_out, l, l == Lc - 1);
    }
}

// Round 8
// 335.708 us; speedup vs baseline: 1.8692x; 1.4299x over previous
//
#include <hip/hip_runtime.h>
#include <hip/hip_bf16.h>

#define Bc 4
#define Tc 16
#define Nc 1024
#define Ec 16384
#define FIN 128
#define Hc 256
#define FFc 1024
#define NHc 8
#define Lc 2
#define HDc 32
#define Gc 64
#define EPSc 1e-5f

typedef __bf16 v8bf __attribute__((ext_vector_type(8)));
typedef float v4f __attribute__((ext_vector_type(4)));

// ---------------- W pack: Wcat[256][256]=[Wl1;Wr1] -> MFMA B-frag order, bf16 hi+lo ----------------
__global__ void pack_w_kernel(const float* __restrict__ Wl, const float* __restrict__ Wr,
                              __bf16* __restrict__ pH, __bf16* __restrict__ pL) {
    int bid = blockIdx.x;            // 0..127 = kc*16+nt
    int t = threadIdx.x;             // 512
    int lane = t >> 3, j = t & 7;
    int kc = bid >> 4, nt = bid & 15;
    int k = kc * 32 + ((lane >> 4) << 3) + j;
    int n = nt * 16 + (lane & 15);
    float w = (k < 128) ? Wl[(size_t)k * Hc + n] : Wr[(size_t)(k - 128) * Hc + n];
    __bf16 hi = (__bf16)w;
    __bf16 lo = (__bf16)(w - (float)hi);
    pH[bid * 512 + t] = hi;
    pL[bid * 512 + t] = lo;
}

// ---------------- per graph: invdeg, cw, CSR(off,elist ushort), zero uv. 1024 thr ----------------
__global__ __launch_bounds__(1024) void csr_kernel(
        const int* __restrict__ ei, float* __restrict__ invdeg, float* __restrict__ cw,
        int* __restrict__ off, unsigned short* __restrict__ elist, float* __restrict__ uv) {
    __shared__ int degs[Nc];
    __shared__ float inv[Nc];
    __shared__ float cl[Nc];
    __shared__ int scan[Nc];
    int g = blockIdx.x, t = threadIdx.x;   // 1024 threads
    const int* src = ei + (size_t)g * 2 * Ec;
    const int* dst = src + Ec;
    if (t < 512) uv[g * 512 + t] = 0.f;
    degs[t] = 0; cl[t] = 0.f;
    __syncthreads();
    for (int e = t; e < Ec; e += 1024) atomicAdd(&degs[dst[e] & (Nc - 1)], 1);
    __syncthreads();
    float iv = 1.0f / fmaxf((float)degs[t], 1.0f);
    inv[t] = iv;
    invdeg[g * Nc + t] = iv;
    __syncthreads();
    for (int e = t; e < Ec; e += 1024) atomicAdd(&cl[src[e] & (Nc - 1)], inv[dst[e] & (Nc - 1)]);
    __syncthreads();
    cw[g * Nc + t] = cl[t];
    // inclusive Hillis-Steele scan of degs
    int own = degs[t];
    scan[t] = own;
    __syncthreads();
    for (int ofs = 1; ofs < 1024; ofs <<= 1) {
        int v = (t >= ofs) ? scan[t - ofs] : 0;
        __syncthreads();
        scan[t] += v;
        __syncthreads();
    }
    int excl = scan[t] - own;
    off[g * 1032 + t] = excl;
    if (t == 1023) off[g * 1032 + Nc] = scan[1023];
    degs[t] = excl;                      // cursors
    __syncthreads();
    for (int e = t; e < Ec; e += 1024) {
        int d = dst[e] & (Nc - 1);
        int slot = atomicAdd(&degs[d], 1);
        elist[(size_t)g * Ec + slot] = (unsigned short)(src[e] & (Nc - 1));
    }
}

// ---------------- SAGE layer1 + reduce: batched gather -> MFMA hi/lo -> u,v. 512 thr ----------------
__global__ __launch_bounds__(512) void sage_kernel(
        const float* __restrict__ x, const unsigned short* __restrict__ elist,
        const int* __restrict__ off, const float* __restrict__ invdeg,
        const float* __restrict__ cw, const __bf16* __restrict__ pH,
        const __bf16* __restrict__ pL, const float* __restrict__ bias,
        float* __restrict__ uv) {
    __shared__ float aggL[32 * 132];     // stride 132 (4-float row skew)
    __shared__ float xL[32 * 132];
    __shared__ float lu[256], lv[256];
    int tid = threadIdx.x;
    int bid = blockIdx.x;                // g*32 + cc
    int g = bid >> 5, cc = bid & 31, r0 = cc * 32;
    const unsigned short* el = elist + (size_t)g * Ec;
    const float* xg = x + (size_t)g * Nc * FIN;
    if (tid < 256) { lu[tid] = 0.f; lv[tid] = 0.f; }

    // phase A: one (row, 8-dim chunk) per thread, edge loop batched by 8
    {
        int lr = tid >> 4, ch = tid & 15;
        int n = r0 + lr;
        int o0 = off[g * 1032 + n], o1 = off[g * 1032 + n + 1];
        float4 a0 = make_float4(0.f, 0.f, 0.f, 0.f);
        float4 a1 = make_float4(0.f, 0.f, 0.f, 0.f);
        const float* xc = xg + ch * 8;
        int e = o0;
        for (; e + 8 <= o1; e += 8) {
            int s[8];
#pragma unroll
            for (int j = 0; j < 8; ++j) s[j] = el[e + j];
            float4 v0[8], v1[8];
#pragma unroll
            for (int j = 0; j < 8; ++j) {
                const float4* xp = (const float4*)(xc + (size_t)s[j] * FIN);
                v0[j] = xp[0]; v1[j] = xp[1];
            }
#pragma unroll
            for (int j = 0; j < 8; ++j) {
                a0.x += v0[j].x; a0.y += v0[j].y; a0.z += v0[j].z; a0.w += v0[j].w;
                a1.x += v1[j].x; a1.y += v1[j].y; a1.z += v1[j].z; a1.w += v1[j].w;
            }
        }
        for (; e < o1; ++e) {
            const float4* xp = (const float4*)(xc + (size_t)el[e] * FIN);
            float4 v0 = xp[0], v1 = xp[1];
            a0.x += v0.x; a0.y += v0.y; a0.z += v0.z; a0.w += v0.w;
            a1.x += v1.x; a1.y += v1.y; a1.z += v1.z; a1.w += v1.w;
        }
        float iv = invdeg[g * Nc + n];
        float* dp = &aggL[lr * 132 + ch * 8];
        dp[0] = a0.x * iv; dp[1] = a0.y * iv; dp[2] = a0.z * iv; dp[3] = a0.w * iv;
        dp[4] = a1.x * iv; dp[5] = a1.y * iv; dp[6] = a1.z * iv; dp[7] = a1.w * iv;
    }
    // stage own-row x tile (float4)
    for (int i = tid; i < 1024; i += 512) {
        int lr = i >> 5, kq = i & 31;
        *(float4*)&xL[lr * 132 + kq * 4] = *(const float4*)&xg[(size_t)(r0 + lr) * FIN + kq * 4];
    }
    __syncthreads();

    // phase B: 8 waves: mt = w&1 (16-row tile), nh = w>>1 (4 n-tiles each)
    int w = tid >> 6, lane = tid & 63, quad = lane >> 4;
    int mt = w & 1, nh = w >> 1;
    int lrow = mt * 16 + (lane & 15);
    v4f acc[4];
#pragma unroll
    for (int i = 0; i < 4; ++i) acc[i] = (v4f)0.f;
    for (int kc = 0; kc < 8; ++kc) {
        const float* ap = (kc < 4) ? &aggL[lrow * 132 + kc * 32 + quad * 8]
                                   : &xL[lrow * 132 + (kc - 4) * 32 + quad * 8];
        float4 f0 = *(const float4*)ap;
        float4 f1 = *(const float4*)(ap + 4);
        float av[8] = {f0.x, f0.y, f0.z, f0.w, f1.x, f1.y, f1.z, f1.w};
        v8bf aH, aL;
#pragma unroll
        for (int j = 0; j < 8; ++j) {
            __bf16 hb = (__bf16)av[j];
            aH[j] = hb;
            aL[j] = (__bf16)(av[j] - (float)hb);
        }
#pragma unroll
        for (int i = 0; i < 4; ++i) {
            int nt = nh * 4 + i;
            v8bf bH = *(const v8bf*)(pH + ((size_t)(kc * 16 + nt) * 64 + lane) * 8);
            v8bf bL = *(const v8bf*)(pL + ((size_t)(kc * 16 + nt) * 64 + lane) * 8);
            acc[i] = __builtin_amdgcn_mfma_f32_16x16x32_bf16(aH, bH, acc[i], 0, 0, 0);
            acc[i] = __builtin_amdgcn_mfma_f32_16x16x32_bf16(aL, bH, acc[i], 0, 0, 0);
            acc[i] = __builtin_amdgcn_mfma_f32_16x16x32_bf16(aH, bL, acc[i], 0, 0, 0);
        }
    }

    // epilogue: bias+relu; u (cw-weighted) / v column sums. C/D: col=lane&15, row=quad*4+r
    float c4[4];
    int nb = g * Nc + r0 + mt * 16 + quad * 4;
#pragma unroll
    for (int r = 0; r < 4; ++r) c4[r] = cw[nb + r];
#pragma unroll
    for (int i = 0; i < 4; ++i) {
        int col = (nh * 4 + i) * 16 + (lane & 15);
        float bcol = bias[col];
        float su = 0.f, sv = 0.f;
#pragma unroll
        for (int r = 0; r < 4; ++r) {
            float val = fmaxf(acc[i][r] + bcol, 0.f);
            sv += val;
            su += c4[r] * val;
        }
        su += __shfl_xor(su, 16); sv += __shfl_xor(sv, 16);
        su += __shfl_xor(su, 32); sv += __shfl_xor(sv, 32);
        if (quad == 0) { atomicAdd(&lu[col], su); atomicAdd(&lv[col], sv); }
    }
    __syncthreads();
    if (tid < 256) {
        atomicAdd(&uv[g * 512 + tid], lu[tid]);
        atomicAdd(&uv[g * 512 + 256 + tid], lv[tid]);
    }
}

// ---------------- emb = u/N @ Wl2 + bl2 + v/N @ Wr2. 512 thr, K split 2 ----------------
__global__ __launch_bounds__(512) void emb_kernel(
        const float* __restrict__ uv, const float* __restrict__ Wl2,
        const float* __restrict__ bl2, const float* __restrict__ Wr2,
        float* __restrict__ h) {
    __shared__ float s[512];
    __shared__ float r2[512];
    int g = blockIdx.x, tid = threadIdx.x;
    s[tid] = uv[g * 512 + tid] * (1.0f / Nc);
    __syncthreads();
    int col = tid & 255, p = tid >> 8;
    float val = 0.f;
    if (p == 0) { for (int k = 0; k < 256; ++k) val += s[k] * Wl2[(size_t)k * Hc + col]; }
    else        { for (int k = 0; k < 256; ++k) val += s[256 + k] * Wr2[(size_t)k * Hc + col]; }
    r2[tid] = val;
    __syncthreads();
    if (tid < 256) h[g * Hc + tid] = bl2[tid] + r2[tid] + r2[tid + 256];
}

// ---------------- qkv: token x seg, 512 thr, K split 2 ----------------
__global__ __launch_bounds__(512) void qkv_kernel(
        const float* __restrict__ h, const float* __restrict__ Wqkv,
        const float* __restrict__ bqkv, float* __restrict__ qkv, int l) {
    __shared__ float hr[256];
    __shared__ float r2[512];
    int bid = blockIdx.x;            // 64 tokens * 3 segs
    int gi = bid / 3, seg = bid % 3;
    int tid = threadIdx.x;
    if (tid < 256) hr[tid] = h[gi * Hc + tid];
    __syncthreads();
    int col = seg * 256 + (tid & 255);
    int half = tid >> 8;
    const float* W = Wqkv + (size_t)l * Hc * 768;
    float val = 0.f;
    int k0 = half * 128;
    for (int k = 0; k < 128; ++k) val += hr[k0 + k] * W[(size_t)(k0 + k) * 768 + col];
    r2[tid] = val;
    __syncthreads();
    if (tid < 256) qkv[gi * 768 + col] = bqkv[(size_t)l * 768 + col] + r2[tid] + r2[tid + 256];
}

// ---------------- attn + proj + ln1 -> h1buf. per-token, 256 thr ----------------
#define KVS 516
__global__ __launch_bounds__(256) void apl_kernel(
        const float* __restrict__ h, const float* __restrict__ qkvg,
        const float* __restrict__ Wo, const float* __restrict__ bo,
        const float* __restrict__ s1, const float* __restrict__ b1ln,
        float* __restrict__ h1buf, int l) {
    __shared__ float kv[16 * KVS];
    __shared__ float q[256];
    __shared__ float sc[8][17];
    __shared__ float ctx[256];
    __shared__ float red[256];
    int t = blockIdx.x, tid = threadIdx.x;
    int b = t >> 4;
    const float* qb = qkvg + (size_t)(b * 16) * 768;
    for (int i = tid; i < 8192; i += 256) {
        int j = i >> 9, d = i & 511;
        kv[j * KVS + d] = qb[(size_t)j * 768 + 256 + d];
    }
    q[tid] = qkvg[(size_t)t * 768 + tid];
    __syncthreads();
    if (tid < 128) {
        int hd = tid >> 4, j = tid & 15;
        float s = 0.f;
#pragma unroll
        for (int d = 0; d < 32; ++d) s += q[hd * 32 + d] * kv[j * KVS + hd * 32 + d];
        sc[hd][j] = s * 0.17677669529663687f;
    }
    __syncthreads();
    if (tid < 8) {
        float m = sc[tid][0];
        for (int j = 1; j < 16; ++j) m = fmaxf(m, sc[tid][j]);
        float e[16], sum = 0.f;
        for (int j = 0; j < 16; ++j) { e[j] = expf(sc[tid][j] - m); sum += e[j]; }
        float inv = 1.0f / sum;
        for (int j = 0; j < 16; ++j) sc[tid][j] = e[j] * inv;
    }
    __syncthreads();
    {
        int hd = tid >> 5, d = tid & 31;
        float o = 0.f;
#pragma unroll
        for (int j = 0; j < 16; ++j) o += sc[hd][j] * kv[j * KVS + 256 + hd * 32 + d];
        ctx[tid] = o;
    }
    __syncthreads();
    const float* W = Wo + (size_t)l * 65536;
    float val = h[(size_t)t * 256 + tid] + bo[(size_t)l * 256 + tid];
    for (int k = 0; k < 256; ++k) val += ctx[k] * W[(size_t)k * 256 + tid];
    red[tid] = val; __syncthreads();
    for (int s = 128; s > 0; s >>= 1) { if (tid < s) red[tid] += red[tid + s]; __syncthreads(); }
    float m1 = red[0] * (1.0f / 256.0f);
    __syncthreads();
    float d1 = val - m1;
    red[tid] = d1 * d1; __syncthreads();
    for (int s = 128; s > 0; s >>= 1) { if (tid < s) red[tid] += red[tid + s]; __syncthreads(); }
    float v1 = red[0] * (1.0f / 256.0f);
    h1buf[(size_t)t * 256 + tid] =
        d1 * rsqrtf(v1 + EPSc) * s1[(size_t)l * 256 + tid] + b1ln[(size_t)l * 256 + tid];
}

// ---------------- ffn1: (token, colgroup) grid 256, 256 thr ----------------
__global__ __launch_bounds__(256) void ffn1_kernel(
        const float* __restrict__ h1buf, const float* __restrict__ W1,
        const float* __restrict__ bf1, float* __restrict__ fL, int l) {
    __shared__ float hr[256];
    int bid = blockIdx.x;
    int t = bid >> 2, cg = bid & 3;
    int tid = threadIdx.x;
    hr[tid] = h1buf[(size_t)t * 256 + tid];
    __syncthreads();
    int col = cg * 256 + tid;
    const float* W = W1 + (size_t)l * 262144;
    float val = bf1[(size_t)l * 1024 + col];
    for (int k = 0; k < 256; ++k) val += hr[k] * W[(size_t)k * 1024 + col];
    fL[(size_t)t * 1024 + col] = fmaxf(val, 0.f);
}

// ---------------- ffn2 + ln2 (+fc): per token, 1024 thr, K split 4 ----------------
__global__ __launch_bounds__(1024) void ffn2_ln_kernel(
        float* __restrict__ h, const float* __restrict__ h1buf, const float* __restrict__ fL,
        const float* __restrict__ W2, const float* __restrict__ bf2,
        const float* __restrict__ s2, const float* __restrict__ b2ln,
        const float* __restrict__ fcW, const float* __restrict__ fcb,
        float* __restrict__ out, int l, int last) {
    __shared__ float fs[1024];
    __shared__ float r4[1024];
    __shared__ float red[256];
    int t = blockIdx.x, tid = threadIdx.x;
    fs[tid] = fL[(size_t)t * 1024 + tid];
    __syncthreads();
    int col = tid & 255, kq = tid >> 8;
    const float* W = W2 + (size_t)l * 262144;
    float p = 0.f;
    int k0 = kq * 256;
    for (int k = 0; k < 256; ++k) p += fs[k0 + k] * W[(size_t)(k0 + k) * 256 + col];
    r4[tid] = p;
    __syncthreads();
    float val = 0.f;
    if (tid < 256) {
        val = h1buf[(size_t)t * 256 + tid] + bf2[(size_t)l * 256 + tid]
            + r4[tid] + r4[tid + 256] + r4[tid + 512] + r4[tid + 768];
        red[tid] = val;
    }
    __syncthreads();
    for (int s = 128; s > 0; s >>= 1) { if (tid < s) red[tid] += red[tid + s]; __syncthreads(); }
    float m2 = red[0] * (1.0f / 256.0f);
    __syncthreads();
    float d2 = (tid < 256) ? (val - m2) : 0.f;
    if (tid < 256) red[tid] = d2 * d2;
    __syncthreads();
    for (int s = 128; s > 0; s >>= 1) { if (tid < s) red[tid] += red[tid + s]; __syncthreads(); }
    float var2 = red[0] * (1.0f / 256.0f);
    float hn = 0.f;
    if (tid < 256) {
        hn = d2 * rsqrtf(var2 + EPSc) * s2[(size_t)l * 256 + tid] + b2ln[(size_t)l * 256 + tid];
        h[(size_t)t * 256 + tid] = hn;
    }
    if (last && (t & 15) == 15) {
        __syncthreads();
        if (tid < 256) red[tid] = hn;
        __syncthreads();
        if (tid < 10) {
            int b = t >> 4;
            float fv = fcb[tid];
            for (int k = 0; k < 256; ++k) fv += red[k] * fcW[(size_t)k * 10 + tid];
            out[b * 10 + tid] = fv;
        }
    }
}

extern "C" void kernel_launch(void* const* d_in, const int* in_sizes, int n_in,
                              void* d_out, int out_size, void* d_ws, size_t ws_size,
                              hipStream_t stream) {
    (void)in_sizes; (void)n_in; (void)out_size; (void)ws_size;
    const float* x    = (const float*)d_in[0];
    const int*   ei   = (const int*)d_in[1];
    const float* s1Wl = (const float*)d_in[2];
    const float* s1bl = (const float*)d_in[3];
    const float* s1Wr = (const float*)d_in[4];
    const float* s2Wl = (const float*)d_in[5];
    const float* s2bl = (const float*)d_in[6];
    const float* s2Wr = (const float*)d_in[7];
    const float* Wqkv = (const float*)d_in[8];
    const float* bqkv = (const float*)d_in[9];
    const float* Wo   = (const float*)d_in[10];
    const float* bo   = (const float*)d_in[11];
    const float* ln1s = (const float*)d_in[12];
    const float* ln1b = (const float*)d_in[13];
    const float* W1   = (const float*)d_in[14];
    const float* b1   = (const float*)d_in[15];
    const float* W2   = (const float*)d_in[16];
    const float* b2   = (const float*)d_in[17];
    const float* ln2s = (const float*)d_in[18];
    const float* ln2b = (const float*)d_in[19];
    const float* fcW  = (const float*)d_in[20];
    const float* fcb  = (const float*)d_in[21];

    // workspace layout (total ~3.87 MB)
    char* ws = (char*)d_ws;
    __bf16*         packWH = (__bf16*)(ws + 0);          // 131072
    __bf16*         packWL = (__bf16*)(ws + 131072);     // 131072
    float*          invdeg = (float*)(ws + 262144);      // 262144
    float*          cw     = (float*)(ws + 524288);      // 262144
    int*            off    = (int*)(ws + 786432);        // 264192
    unsigned short* elist  = (unsigned short*)(ws + 1050624); // 2097152
    float*          uv     = (float*)(ws + 3147776);     // 131072
    float*          h      = (float*)(ws + 3278848);     // 65536
    float*          qkvg   = (float*)(ws + 3344384);     // 196608
    float*          h1buf  = (float*)(ws + 3540992);     // 65536
    float*          fLbuf  = (float*)(ws + 3606528);     // 262144
                                                         // end = 3868672

    pack_w_kernel<<<128, 512, 0, stream>>>(s1Wl, s1Wr, packWH, packWL);
    csr_kernel<<<Gc, 1024, 0, stream>>>(ei, invdeg, cw, off, elist, uv);
    sage_kernel<<<Gc * 32, 512, 0, stream>>>(x, elist, off, invdeg, cw, packWH, packWL, s1bl, uv);
    emb_kernel<<<Gc, 512, 0, stream>>>(uv, s2Wl, s2bl, s2Wr, h);
    for (int l = 0; l < Lc; ++l) {
        qkv_kernel<<<Gc * 3, 512, 0, stream>>>(h, Wqkv, bqkv, qkvg, l);
        apl_kernel<<<Gc, 256, 0, stream>>>(h, qkvg, Wo, bo, ln1s, ln1b, h1buf, l);
        ffn1_kernel<<<Gc * 4, 256, 0, stream>>>(h1buf, W1, b1, fLbuf, l);
        ffn2_ln_kernel<<<Gc, 1024, 0, stream>>>(h, h1buf, fLbuf, W2, b2, ln2s, ln2b,
                                                fcW, fcb, (float*)d_out, l, l == Lc - 1);
    }
}

// Round 9
// 313.309 us; speedup vs baseline: 2.0028x; 1.0715x over previous
//
#include <hip/hip_runtime.h>
#include <hip/hip_bf16.h>

#define Bc 4
#define Tc 16
#define Nc 1024
#define Ec 16384
#define FIN 128
#define Hc 256
#define FFc 1024
#define NHc 8
#define Lc 2
#define HDc 32
#define Gc 64
#define EPSc 1e-5f

typedef __bf16 v8bf __attribute__((ext_vector_type(8)));
typedef float v4f __attribute__((ext_vector_type(4)));

// ---------------- W pack: Wcat[256][256]=[Wl1;Wr1] -> MFMA B-frag order, bf16 hi+lo ----------------
__global__ void pack_w_kernel(const float* __restrict__ Wl, const float* __restrict__ Wr,
                              __bf16* __restrict__ pH, __bf16* __restrict__ pL) {
    int bid = blockIdx.x;            // 0..127 = kc*16+nt
    int t = threadIdx.x;             // 512
    int lane = t >> 3, j = t & 7;
    int kc = bid >> 4, nt = bid & 15;
    int k = kc * 32 + ((lane >> 4) << 3) + j;
    int n = nt * 16 + (lane & 15);
    float w = (k < 128) ? Wl[(size_t)k * Hc + n] : Wr[(size_t)(k - 128) * Hc + n];
    __bf16 hi = (__bf16)w;
    __bf16 lo = (__bf16)(w - (float)hi);
    pH[bid * 512 + t] = hi;
    pL[bid * 512 + t] = lo;
}

// ---------------- per graph: invdeg, cw, CSR(off,elist ushort), zero uv. 1024 thr ----------------
__global__ __launch_bounds__(1024) void csr_kernel(
        const int* __restrict__ ei, float* __restrict__ invdeg, float* __restrict__ cw,
        int* __restrict__ off, unsigned short* __restrict__ elist, float* __restrict__ uv) {
    __shared__ int degs[Nc];
    __shared__ float inv[Nc];
    __shared__ float cl[Nc];
    __shared__ int wsum[16];
    int g = blockIdx.x, t = threadIdx.x;   // 1024 threads
    const int* src = ei + (size_t)g * 2 * Ec;
    const int* dst = src + Ec;
    if (t < 512) uv[g * 512 + t] = 0.f;
    degs[t] = 0; cl[t] = 0.f;
    __syncthreads();
    for (int e = t; e < Ec; e += 1024) atomicAdd(&degs[dst[e] & (Nc - 1)], 1);
    __syncthreads();
    float iv = 1.0f / fmaxf((float)degs[t], 1.0f);
    inv[t] = iv;
    invdeg[g * Nc + t] = iv;
    __syncthreads();
    for (int e = t; e < Ec; e += 1024) atomicAdd(&cl[src[e] & (Nc - 1)], inv[dst[e] & (Nc - 1)]);
    __syncthreads();
    cw[g * Nc + t] = cl[t];
    // wave-level inclusive scan of degs (16 waves of 64)
    int own = degs[t];
    int lane = t & 63, wv = t >> 6;
    int val = own;
#pragma unroll
    for (int ofs = 1; ofs < 64; ofs <<= 1) {
        int v = __shfl_up(val, ofs, 64);
        if (lane >= ofs) val += v;
    }
    if (lane == 63) wsum[wv] = val;
    __syncthreads();
    if (wv == 0 && lane < 16) {
        int wval = wsum[lane];
#pragma unroll
        for (int ofs = 1; ofs < 16; ofs <<= 1) {
            int v = __shfl_up(wval, ofs, 64);
            if (lane >= ofs) wval += v;
        }
        wsum[lane] = wval;
    }
    __syncthreads();
    int incl = val + ((wv > 0) ? wsum[wv - 1] : 0);
    int excl = incl - own;
    off[g * 1032 + t] = excl;
    if (t == 1023) off[g * 1032 + Nc] = incl;
    degs[t] = excl;                      // cursors
    __syncthreads();
    for (int e = t; e < Ec; e += 1024) {
        int d = dst[e] & (Nc - 1);
        int slot = atomicAdd(&degs[d], 1);
        elist[(size_t)g * Ec + slot] = (unsigned short)(src[e] & (Nc - 1));
    }
}

// ---------------- SAGE layer1 + reduce: XCD-swizzled, gather -> MFMA hi/lo -> u,v ----------------
__global__ __launch_bounds__(512) void sage_kernel(
        const float* __restrict__ x, const unsigned short* __restrict__ elist,
        const int* __restrict__ off, const float* __restrict__ invdeg,
        const float* __restrict__ cw, const __bf16* __restrict__ pH,
        const __bf16* __restrict__ pL, const float* __restrict__ bias,
        float* __restrict__ uv) {
    __shared__ float aggL[32 * 132];     // stride 132 (4-float row skew)
    __shared__ float xL[32 * 132];
    __shared__ float lu[256], lv[256];
    int tid = threadIdx.x;
    int bid = blockIdx.x;
    // XCD swizzle: bid = cc*64 + g  => all 32 blocks of graph g share bid%8 (same XCD L2)
    int g = bid & 63, cc = bid >> 6, r0 = cc * 32;
    const unsigned short* el = elist + (size_t)g * Ec;
    const float* xg = x + (size_t)g * Nc * FIN;
    if (tid < 256) { lu[tid] = 0.f; lv[tid] = 0.f; }

    // phase A: one (row, 8-dim chunk) per thread, edge loop batched by 8
    {
        int lr = tid >> 4, ch = tid & 15;
        int n = r0 + lr;
        int o0 = off[g * 1032 + n], o1 = off[g * 1032 + n + 1];
        float4 a0 = make_float4(0.f, 0.f, 0.f, 0.f);
        float4 a1 = make_float4(0.f, 0.f, 0.f, 0.f);
        const float* xc = xg + ch * 8;
        int e = o0;
        for (; e + 8 <= o1; e += 8) {
            int s[8];
#pragma unroll
            for (int j = 0; j < 8; ++j) s[j] = el[e + j];
            float4 v0[8], v1[8];
#pragma unroll
            for (int j = 0; j < 8; ++j) {
                const float4* xp = (const float4*)(xc + (size_t)s[j] * FIN);
                v0[j] = xp[0]; v1[j] = xp[1];
            }
#pragma unroll
            for (int j = 0; j < 8; ++j) {
                a0.x += v0[j].x; a0.y += v0[j].y; a0.z += v0[j].z; a0.w += v0[j].w;
                a1.x += v1[j].x; a1.y += v1[j].y; a1.z += v1[j].z; a1.w += v1[j].w;
            }
        }
        for (; e < o1; ++e) {
            const float4* xp = (const float4*)(xc + (size_t)el[e] * FIN);
            float4 v0 = xp[0], v1 = xp[1];
            a0.x += v0.x; a0.y += v0.y; a0.z += v0.z; a0.w += v0.w;
            a1.x += v1.x; a1.y += v1.y; a1.z += v1.z; a1.w += v1.w;
        }
        float iv = invdeg[g * Nc + n];
        float* dp = &aggL[lr * 132 + ch * 8];
        dp[0] = a0.x * iv; dp[1] = a0.y * iv; dp[2] = a0.z * iv; dp[3] = a0.w * iv;
        dp[4] = a1.x * iv; dp[5] = a1.y * iv; dp[6] = a1.z * iv; dp[7] = a1.w * iv;
    }
    // stage own-row x tile (float4)
    for (int i = tid; i < 1024; i += 512) {
        int lr = i >> 5, kq = i & 31;
        *(float4*)&xL[lr * 132 + kq * 4] = *(const float4*)&xg[(size_t)(r0 + lr) * FIN + kq * 4];
    }
    __syncthreads();

    // phase B: 8 waves: mt = w&1 (16-row tile), nh = w>>1 (4 n-tiles each)
    int w = tid >> 6, lane = tid & 63, quad = lane >> 4;
    int mt = w & 1, nh = w >> 1;
    int lrow = mt * 16 + (lane & 15);
    v4f acc[4];
#pragma unroll
    for (int i = 0; i < 4; ++i) acc[i] = (v4f)0.f;
    for (int kc = 0; kc < 8; ++kc) {
        const float* ap = (kc < 4) ? &aggL[lrow * 132 + kc * 32 + quad * 8]
                                   : &xL[lrow * 132 + (kc - 4) * 32 + quad * 8];
        float4 f0 = *(const float4*)ap;
        float4 f1 = *(const float4*)(ap + 4);
        float av[8] = {f0.x, f0.y, f0.z, f0.w, f1.x, f1.y, f1.z, f1.w};
        v8bf aH, aL;
#pragma unroll
        for (int j = 0; j < 8; ++j) {
            __bf16 hb = (__bf16)av[j];
            aH[j] = hb;
            aL[j] = (__bf16)(av[j] - (float)hb);
        }
#pragma unroll
        for (int i = 0; i < 4; ++i) {
            int nt = nh * 4 + i;
            v8bf bH = *(const v8bf*)(pH + ((size_t)(kc * 16 + nt) * 64 + lane) * 8);
            v8bf bL = *(const v8bf*)(pL + ((size_t)(kc * 16 + nt) * 64 + lane) * 8);
            acc[i] = __builtin_amdgcn_mfma_f32_16x16x32_bf16(aH, bH, acc[i], 0, 0, 0);
            acc[i] = __builtin_amdgcn_mfma_f32_16x16x32_bf16(aL, bH, acc[i], 0, 0, 0);
            acc[i] = __builtin_amdgcn_mfma_f32_16x16x32_bf16(aH, bL, acc[i], 0, 0, 0);
        }
    }

    // epilogue: bias+relu; u (cw-weighted) / v column sums. C/D: col=lane&15, row=quad*4+r
    float c4[4];
    int nb = g * Nc + r0 + mt * 16 + quad * 4;
#pragma unroll
    for (int r = 0; r < 4; ++r) c4[r] = cw[nb + r];
#pragma unroll
    for (int i = 0; i < 4; ++i) {
        int col = (nh * 4 + i) * 16 + (lane & 15);
        float bcol = bias[col];
        float su = 0.f, sv = 0.f;
#pragma unroll
        for (int r = 0; r < 4; ++r) {
            float val = fmaxf(acc[i][r] + bcol, 0.f);
            sv += val;
            su += c4[r] * val;
        }
        su += __shfl_xor(su, 16); sv += __shfl_xor(sv, 16);
        su += __shfl_xor(su, 32); sv += __shfl_xor(sv, 32);
        if (quad == 0) { atomicAdd(&lu[col], su); atomicAdd(&lv[col], sv); }
    }
    __syncthreads();
    if (tid < 256) {
        atomicAdd(&uv[g * 512 + tid], lu[tid]);
        atomicAdd(&uv[g * 512 + 256 + tid], lv[tid]);
    }
}

// ---------------- emb = u/N @ Wl2 + bl2 + v/N @ Wr2. 512 thr, K split 2 ----------------
__global__ __launch_bounds__(512) void emb_kernel(
        const float* __restrict__ uv, const float* __restrict__ Wl2,
        const float* __restrict__ bl2, const float* __restrict__ Wr2,
        float* __restrict__ h) {
    __shared__ float s[512];
    __shared__ float r2[512];
    int g = blockIdx.x, tid = threadIdx.x;
    s[tid] = uv[g * 512 + tid] * (1.0f / Nc);
    __syncthreads();
    int col = tid & 255, p = tid >> 8;
    float val = 0.f;
    if (p == 0) { for (int k = 0; k < 256; ++k) val += s[k] * Wl2[(size_t)k * Hc + col]; }
    else        { for (int k = 0; k < 256; ++k) val += s[256 + k] * Wr2[(size_t)k * Hc + col]; }
    r2[tid] = val;
    __syncthreads();
    if (tid < 256) h[g * Hc + tid] = bl2[tid] + r2[tid] + r2[tid + 256];
}

// ---------------- qkv: token x seg, 512 thr, K split 2 ----------------
__global__ __launch_bounds__(512) void qkv_kernel(
        const float* __restrict__ h, const float* __restrict__ Wqkv,
        const float* __restrict__ bqkv, float* __restrict__ qkv, int l) {
    __shared__ float hr[256];
    __shared__ float r2[512];
    int bid = blockIdx.x;            // 64 tokens * 3 segs
    int gi = bid / 3, seg = bid % 3;
    int tid = threadIdx.x;
    if (tid < 256) hr[tid] = h[gi * Hc + tid];
    __syncthreads();
    int col = seg * 256 + (tid & 255);
    int half = tid >> 8;
    const float* W = Wqkv + (size_t)l * Hc * 768;
    float val = 0.f;
    int k0 = half * 128;
    for (int k = 0; k < 128; ++k) val += hr[k0 + k] * W[(size_t)(k0 + k) * 768 + col];
    r2[tid] = val;
    __syncthreads();
    if (tid < 256) qkv[gi * 768 + col] = bqkv[(size_t)l * 768 + col] + r2[tid] + r2[tid + 256];
}

// ---------------- attn + proj + ln1 -> h1buf. per-token, 512 thr, proj K-split 2 ----------------
#define KVS 516
__global__ __launch_bounds__(512) void apl_kernel(
        const float* __restrict__ h, const float* __restrict__ qkvg,
        const float* __restrict__ Wo, const float* __restrict__ bo,
        const float* __restrict__ s1, const float* __restrict__ b1ln,
        float* __restrict__ h1buf, int l) {
    __shared__ float kv[16 * KVS];
    __shared__ float q[256];
    __shared__ float sc[8][17];
    __shared__ float ctx[256];
    __shared__ float r2[512];
    __shared__ float red[256];
    int t = blockIdx.x, tid = threadIdx.x;
    int b = t >> 4;
    const float* qb = qkvg + (size_t)(b * 16) * 768;
    for (int i = tid; i < 8192; i += 512) {
        int j = i >> 9, d = i & 511;
        kv[j * KVS + d] = qb[(size_t)j * 768 + 256 + d];
    }
    if (tid < 256) q[tid] = qkvg[(size_t)t * 768 + tid];
    __syncthreads();
    if (tid < 128) {
        int hd = tid >> 4, j = tid & 15;
        float s = 0.f;
#pragma unroll
        for (int d = 0; d < 32; ++d) s += q[hd * 32 + d] * kv[j * KVS + hd * 32 + d];
        sc[hd][j] = s * 0.17677669529663687f;
    }
    __syncthreads();
    if (tid < 8) {
        float m = sc[tid][0];
        for (int j = 1; j < 16; ++j) m = fmaxf(m, sc[tid][j]);
        float e[16], sum = 0.f;
        for (int j = 0; j < 16; ++j) { e[j] = expf(sc[tid][j] - m); sum += e[j]; }
        float inv = 1.0f / sum;
        for (int j = 0; j < 16; ++j) sc[tid][j] = e[j] * inv;
    }
    __syncthreads();
    if (tid < 256) {
        int hd = tid >> 5, d = tid & 31;
        float o = 0.f;
#pragma unroll
        for (int j = 0; j < 16; ++j) o += sc[hd][j] * kv[j * KVS + 256 + hd * 32 + d];
        ctx[tid] = o;
    }
    __syncthreads();
    // proj: K split 2 over 512 threads
    int col = tid & 255, half = tid >> 8;
    const float* W = Wo + (size_t)l * 65536;
    float pv = 0.f;
    int k0 = half * 128;
    for (int k = 0; k < 128; ++k) pv += ctx[k0 + k] * W[(size_t)(k0 + k) * 256 + col];
    r2[tid] = pv;
    __syncthreads();
    float val = 0.f;
    if (tid < 256) {
        val = h[(size_t)t * 256 + tid] + bo[(size_t)l * 256 + tid] + r2[tid] + r2[tid + 256];
        red[tid] = val;
    }
    __syncthreads();
    for (int s = 128; s > 0; s >>= 1) { if (tid < s) red[tid] += red[tid + s]; __syncthreads(); }
    float m1 = red[0] * (1.0f / 256.0f);
    __syncthreads();
    float d1 = val - m1;
    if (tid < 256) red[tid] = d1 * d1;
    __syncthreads();
    for (int s = 128; s > 0; s >>= 1) { if (tid < s) red[tid] += red[tid + s]; __syncthreads(); }
    float v1 = red[0] * (1.0f / 256.0f);
    if (tid < 256)
        h1buf[(size_t)t * 256 + tid] =
            d1 * rsqrtf(v1 + EPSc) * s1[(size_t)l * 256 + tid] + b1ln[(size_t)l * 256 + tid];
}

// ---------------- ffn1: (token, colgroup) grid 256, 512 thr, K split 2 ----------------
__global__ __launch_bounds__(512) void ffn1_kernel(
        const float* __restrict__ h1buf, const float* __restrict__ W1,
        const float* __restrict__ bf1, float* __restrict__ fL, int l) {
    __shared__ float hr[256];
    __shared__ float r2[512];
    int bid = blockIdx.x;
    int t = bid >> 2, cg = bid & 3;
    int tid = threadIdx.x;
    if (tid < 256) hr[tid] = h1buf[(size_t)t * 256 + tid];
    __syncthreads();
    int col = cg * 256 + (tid & 255);
    int half = tid >> 8;
    const float* W = W1 + (size_t)l * 262144;
    float val = 0.f;
    int k0 = half * 128;
    for (int k = 0; k < 128; ++k) val += hr[k0 + k] * W[(size_t)(k0 + k) * 1024 + col];
    r2[tid] = val;
    __syncthreads();
    if (tid < 256)
        fL[(size_t)t * 1024 + col] = fmaxf(bf1[(size_t)l * 1024 + col] + r2[tid] + r2[tid + 256], 0.f);
}

// ---------------- ffn2 + ln2 (+fc): per token, 1024 thr, K split 4 ----------------
__global__ __launch_bounds__(1024) void ffn2_ln_kernel(
        float* __restrict__ h, const float* __restrict__ h1buf, const float* __restrict__ fL,
        const float* __restrict__ W2, const float* __restrict__ bf2,
        const float* __restrict__ s2, const float* __restrict__ b2ln,
        const float* __restrict__ fcW, const float* __restrict__ fcb,
        float* __restrict__ out, int l, int last) {
    __shared__ float fs[1024];
    __shared__ float r4[1024];
    __shared__ float red[256];
    int t = blockIdx.x, tid = threadIdx.x;
    fs[tid] = fL[(size_t)t * 1024 + tid];
    __syncthreads();
    int col = tid & 255, kq = tid >> 8;
    const float* W = W2 + (size_t)l * 262144;
    float p = 0.f;
    int k0 = kq * 256;
    for (int k = 0; k < 256; ++k) p += fs[k0 + k] * W[(size_t)(k0 + k) * 256 + col];
    r4[tid] = p;
    __syncthreads();
    float val = 0.f;
    if (tid < 256) {
        val = h1buf[(size_t)t * 256 + tid] + bf2[(size_t)l * 256 + tid]
            + r4[tid] + r4[tid + 256] + r4[tid + 512] + r4[tid + 768];
        red[tid] = val;
    }
    __syncthreads();
    for (int s = 128; s > 0; s >>= 1) { if (tid < s) red[tid] += red[tid + s]; __syncthreads(); }
    float m2 = red[0] * (1.0f / 256.0f);
    __syncthreads();
    float d2 = (tid < 256) ? (val - m2) : 0.f;
    if (tid < 256) red[tid] = d2 * d2;
    __syncthreads();
    for (int s = 128; s > 0; s >>= 1) { if (tid < s) red[tid] += red[tid + s]; __syncthreads(); }
    float var2 = red[0] * (1.0f / 256.0f);
    float hn = 0.f;
    if (tid < 256) {
        hn = d2 * rsqrtf(var2 + EPSc) * s2[(size_t)l * 256 + tid] + b2ln[(size_t)l * 256 + tid];
        h[(size_t)t * 256 + tid] = hn;
    }
    if (last && (t & 15) == 15) {
        __syncthreads();
        if (tid < 256) red[tid] = hn;
        __syncthreads();
        if (tid < 10) {
            int b = t >> 4;
            float fv = fcb[tid];
            for (int k = 0; k < 256; ++k) fv += red[k] * fcW[(size_t)k * 10 + tid];
            out[b * 10 + tid] = fv;
        }
    }
}

extern "C" void kernel_launch(void* const* d_in, const int* in_sizes, int n_in,
                              void* d_out, int out_size, void* d_ws, size_t ws_size,
                              hipStream_t stream) {
    (void)in_sizes; (void)n_in; (void)out_size; (void)ws_size;
    const float* x    = (const float*)d_in[0];
    const int*   ei   = (const int*)d_in[1];
    const float* s1Wl = (const float*)d_in[2];
    const float* s1bl = (const float*)d_in[3];
    const float* s1Wr = (const float*)d_in[4];
    const float* s2Wl = (const float*)d_in[5];
    const float* s2bl = (const float*)d_in[6];
    const float* s2Wr = (const float*)d_in[7];
    const float* Wqkv = (const float*)d_in[8];
    const float* bqkv = (const float*)d_in[9];
    const float* Wo   = (const float*)d_in[10];
    const float* bo   = (const float*)d_in[11];
    const float* ln1s = (const float*)d_in[12];
    const float* ln1b = (const float*)d_in[13];
    const float* W1   = (const float*)d_in[14];
    const float* b1   = (const float*)d_in[15];
    const float* W2   = (const float*)d_in[16];
    const float* b2   = (const float*)d_in[17];
    const float* ln2s = (const float*)d_in[18];
    const float* ln2b = (const float*)d_in[19];
    const float* fcW  = (const float*)d_in[20];
    const float* fcb  = (const float*)d_in[21];

    // workspace layout (total ~3.87 MB)
    char* ws = (char*)d_ws;
    __bf16*         packWH = (__bf16*)(ws + 0);          // 131072
    __bf16*         packWL = (__bf16*)(ws + 131072);     // 131072
    float*          invdeg = (float*)(ws + 262144);      // 262144
    float*          cw     = (float*)(ws + 524288);      // 262144
    int*            off    = (int*)(ws + 786432);        // 264192
    unsigned short* elist  = (unsigned short*)(ws + 1050624); // 2097152
    float*          uv     = (float*)(ws + 3147776);     // 131072
    float*          h      = (float*)(ws + 3278848);     // 65536
    float*          qkvg   = (float*)(ws + 3344384);     // 196608
    float*          h1buf  = (float*)(ws + 3540992);     // 65536
    float*          fLbuf  = (float*)(ws + 3606528);     // 262144
                                                         // end = 3868672

    pack_w_kernel<<<128, 512, 0, stream>>>(s1Wl, s1Wr, packWH, packWL);
    csr_kernel<<<Gc, 1024, 0, stream>>>(ei, invdeg, cw, off, elist, uv);
    sage_kernel<<<Gc * 32, 512, 0, stream>>>(x, elist, off, invdeg, cw, packWH, packWL, s1bl, uv);
    emb_kernel<<<Gc, 512, 0, stream>>>(uv, s2Wl, s2bl, s2Wr, h);
    for (int l = 0; l < Lc; ++l) {
        qkv_kernel<<<Gc * 3, 512, 0, stream>>>(h, Wqkv, bqkv, qkvg, l);
        apl_kernel<<<Gc, 512, 0, stream>>>(h, qkvg, Wo, bo, ln1s, ln1b, h1buf, l);
        ffn1_kernel<<<Gc * 4, 512, 0, stream>>>(h1buf, W1, b1, fLbuf, l);
        ffn2_ln_kernel<<<Gc, 1024, 0, stream>>>(h, h1buf, fLbuf, W2, b2, ln2s, ln2b,
                                                fcW, fcb, (float*)d_out, l, l == Lc - 1);
    }
}